// Round 2
// baseline (856.235 us; speedup 1.0000x reference)
//
#include <hip/hip_runtime.h>
#include <hip/hip_bf16.h>
#include <stdint.h>

#define M_TOK 4096
#define IN_K  4096
#define OUT_N 11008
#define NGRP  32

#define BM 128
#define BN 128
#define BK 64
#define NT (IN_K / BK)

typedef short bf16x8 __attribute__((ext_vector_type(8)));
typedef float f32x4  __attribute__((ext_vector_type(4)));
typedef unsigned short u16;
typedef unsigned int   u32;

__device__ __forceinline__ void glds16(const void* g, void* l) {
  __builtin_amdgcn_global_load_lds(
      (const __attribute__((address_space(1))) u32*)g,
      (__attribute__((address_space(3))) u32*)l, 16, 0, 0);
}

__device__ __forceinline__ u16 f2b(float f) {
  __hip_bfloat16 h = __float2bfloat16(f);
  return *(u16*)&h;
}
__device__ __forceinline__ u32 pack2(float a, float b) {
  return (u32)f2b(a) | ((u32)f2b(b) << 16);
}

// tab[p] = (cb[p & 15], cb[p >> 4])  -- both nibbles dequantized in one 8B read
__global__ void build_tab_kernel(const float* __restrict__ cb, float2* __restrict__ tab) {
  int t = threadIdx.x;
  tab[t] = make_float2(cb[t & 15], cb[(t >> 4) & 15]);
}

// y[m][grp*128+g] = sum_h x[m][grp*128+h] * rot[h*128+g], stored bf16.
// MFMA 16x16x32: A = x-tile [64 x 128] (bf16), B from Rt[g][h] ([N][K] layout).
__global__ __launch_bounds__(256)
void rotate_kernel(const float* __restrict__ x, const float* __restrict__ rot,
                   u16* __restrict__ y) {
  __shared__ u16 Xs[64 * 128];    // [m][h], 16 KB, chunk-XOR swizzled
  __shared__ u16 Rt[128 * 128];   // [g][h], 32 KB, chunk-XOR swizzled
  const int t = threadIdx.x;
  const int m0 = blockIdx.x * 64;
  const int grp = blockIdx.y;

  for (int i = t; i < 128 * 128; i += 256) {           // rot[h*128+g] -> Rt[g][h]
    int h = i >> 7, g = i & 127;
    Rt[g * 128 + ((((h >> 3) ^ (g & 7)) << 3) | (h & 7))] = f2b(rot[i]);
  }
  for (int i = t; i < 64 * 128; i += 256) {
    int m = i >> 7, h = i & 127;
    Xs[m * 128 + ((((h >> 3) ^ (m & 7)) << 3) | (h & 7))] =
        f2b(x[(size_t)(m0 + m) * IN_K + grp * 128 + h]);
  }
  __syncthreads();

  const int lane = t & 63;
  const int wv = t >> 6;        // 4 waves, each owns 32 g-columns
  const int wn = wv * 32;
  const int fr = lane & 15;
  const int q = lane >> 4;
  const int sw = fr & 7;

  f32x4 acc[4][2] = {};
#pragma unroll
  for (int ks = 0; ks < 4; ++ks) {
    bf16x8 av[4], bv[2];
#pragma unroll
    for (int fi = 0; fi < 4; ++fi)
      av[fi] = *(const bf16x8*)&Xs[(fi * 16 + fr) * 128 + (((ks * 4 + q) ^ sw) << 3)];
#pragma unroll
    for (int fj = 0; fj < 2; ++fj)
      bv[fj] = *(const bf16x8*)&Rt[(wn + fj * 16 + fr) * 128 + (((ks * 4 + q) ^ sw) << 3)];
#pragma unroll
    for (int fi = 0; fi < 4; ++fi)
#pragma unroll
      for (int fj = 0; fj < 2; ++fj)
        acc[fi][fj] = __builtin_amdgcn_mfma_f32_16x16x32_bf16(av[fi], bv[fj], acc[fi][fj], 0, 0, 0);
  }
#pragma unroll
  for (int fi = 0; fi < 4; ++fi)
#pragma unroll
    for (int fj = 0; fj < 2; ++fj)
#pragma unroll
      for (int rr = 0; rr < 4; ++rr)
        y[(size_t)(m0 + fi * 16 + q * 4 + rr) * IN_K + grp * 128 + wn + fj * 16 + fr] =
            f2b(acc[fi][fj][rr]);
}

// w'[o][k] = cb[idx[o][k]] * norms[o][k/128], bf16. One block per output row.
__global__ __launch_bounds__(256)
void dequant_kernel(const int* __restrict__ packed, const float* __restrict__ norms,
                    const float2* __restrict__ tab, u16* __restrict__ wp) {
  const int o = blockIdx.x;
  const int t = threadIdx.x;
  const int* pb = packed + (size_t)o * (IN_K / 2) + t * 8;
  const float nm = norms[o * NGRP + (t >> 3)];
  int4 a = ((const int4*)pb)[0];
  int4 b = ((const int4*)pb)[1];
  int ps[8] = {a.x, a.y, a.z, a.w, b.x, b.y, b.z, b.w};
  u32 w[8];
#pragma unroll
  for (int j = 0; j < 8; ++j) {
    float2 c2 = tab[ps[j]];
    w[j] = pack2(c2.x * nm, c2.y * nm);
  }
  u32* dst = (u32*)(wp + (size_t)o * IN_K + t * 16);
  ((uint4*)dst)[0] = make_uint4(w[0], w[1], w[2], w[3]);
  ((uint4*)dst)[1] = make_uint4(w[4], w[5], w[6], w[7]);
}

// C[m][n] = sum_k y[m][k] * w'[n][k] + bias[n].
// 128x128 tile, BK=64, 4 waves (2x2 of 64x64), mfma 16x16x32 bf16,
// double-buffered LDS, global_load_lds staging with pre-swizzled source.
template <bool PRE>
__global__ __launch_bounds__(256, 2)
void gemm_kernel(const u16* __restrict__ A, const u16* __restrict__ Bw,
                 const int* __restrict__ packed, const float2* __restrict__ tab,
                 const float* __restrict__ norms, const float* __restrict__ bias,
                 float* __restrict__ C) {
  __shared__ u16 As[2][BM * BK];   // 2 x 16 KB
  __shared__ u16 Bs[2][BM * BK];   // 2 x 16 KB  (total exactly 64 KB)

  const int t = threadIdx.x;
  const int m0 = blockIdx.x * BM;
  const int n0 = blockIdx.y * BN;

  // glds staging geometry: issue i covers rows i*32..i*32+31; thread t -> row t/8,
  // 16B-chunk t%8. Source column pre-swizzled so LDS stays linear (m173 pattern).
  const int srow = t >> 3;
  const int scol = (((t & 7) ^ (srow & 7)) << 3);   // element offset within BK
  const u32 luni = (u32)(t & 192) * 16;             // wave-uniform LDS byte base

  // fused-dequant geometry: 2 threads per B row, 32 k each
  const int fro = t >> 1;
  const int kh = t & 1;

  const int lane = t & 63;
  const int wv = t >> 6;
  const int wm = (wv >> 1) * 64;
  const int wn = (wv & 1) * 64;
  const int fr = lane & 15;
  const int q = lane >> 4;
  const int sw = fr & 7;

  f32x4 acc[4][4] = {};
  int4 pk[4];

  auto stageA = [&](int buf, int kt) {
#pragma unroll
    for (int i = 0; i < 4; ++i)
      glds16(A + (size_t)(m0 + i * 32 + srow) * IN_K + kt * BK + scol,
             (char*)(&As[buf][0]) + i * 4096 + luni);
  };
  auto stageBpre = [&](int buf, int kt) {
#pragma unroll
    for (int i = 0; i < 4; ++i)
      glds16(Bw + (size_t)(n0 + i * 32 + srow) * IN_K + kt * BK + scol,
             (char*)(&Bs[buf][0]) + i * 4096 + luni);
  };
  auto loadBidx = [&](int kt) {
    const int4* pb =
        (const int4*)(packed + (size_t)(n0 + fro) * (IN_K / 2) + kt * (BK / 2) + kh * 16);
#pragma unroll
    for (int i = 0; i < 4; ++i) pk[i] = pb[i];
  };
  auto dequantB = [&](int buf, int kt) {
    const float nm = norms[(n0 + fro) * NGRP + (kt >> 1)];
#pragma unroll
    for (int jj = 0; jj < 4; ++jj) {
      int pv[4] = {pk[jj].x, pk[jj].y, pk[jj].z, pk[jj].w};
      u32 w[4];
#pragma unroll
      for (int qq = 0; qq < 4; ++qq) {
        float2 c2 = tab[pv[qq]];
        w[qq] = pack2(c2.x * nm, c2.y * nm);
      }
      uint4* dst = (uint4*)((char*)(&Bs[buf][0]) + fro * (BK * 2) +
                            (((kh * 4 + jj) ^ (fro & 7)) << 4));
      *dst = make_uint4(w[0], w[1], w[2], w[3]);
    }
  };
  auto compute = [&](int buf) {
#pragma unroll
    for (int ks = 0; ks < 2; ++ks) {
      bf16x8 av[4], bv[4];
#pragma unroll
      for (int fi = 0; fi < 4; ++fi)
        av[fi] = *(const bf16x8*)&As[buf][(wm + fi * 16 + fr) * BK + (((ks * 4 + q) ^ sw) << 3)];
#pragma unroll
      for (int fj = 0; fj < 4; ++fj)
        bv[fj] = *(const bf16x8*)&Bs[buf][(wn + fj * 16 + fr) * BK + (((ks * 4 + q) ^ sw) << 3)];
#pragma unroll
      for (int fi = 0; fi < 4; ++fi)
#pragma unroll
        for (int fj = 0; fj < 4; ++fj)
          acc[fi][fj] =
              __builtin_amdgcn_mfma_f32_16x16x32_bf16(av[fi], bv[fj], acc[fi][fj], 0, 0, 0);
    }
  };

  int buf = 0;
  stageA(0, 0);
  if (PRE) {
    stageBpre(0, 0);
  } else {
    loadBidx(0);
    dequantB(0, 0);
  }
  __syncthreads();

  for (int kt = 0; kt < NT; ++kt) {
    const int nxt = kt + 1;
    if (nxt < NT) {
      stageA(buf ^ 1, nxt);
      if (PRE) stageBpre(buf ^ 1, nxt);
      else loadBidx(nxt);
    }
    compute(buf);
    if (!PRE && nxt < NT) dequantB(buf ^ 1, nxt);
    __syncthreads();
    buf ^= 1;
  }

#pragma unroll
  for (int fj = 0; fj < 4; ++fj) {
    const int col = n0 + wn + fj * 16 + fr;
    const float bv = bias[col];
#pragma unroll
    for (int fi = 0; fi < 4; ++fi) {
      const int row = m0 + wm + fi * 16 + q * 4;
#pragma unroll
      for (int rr = 0; rr < 4; ++rr)
        C[(size_t)(row + rr) * OUT_N + col] = acc[fi][fj][rr] + bv;
    }
  }
}

extern "C" void kernel_launch(void* const* d_in, const int* in_sizes, int n_in,
                              void* d_out, int out_size, void* d_ws, size_t ws_size,
                              hipStream_t stream) {
  const float* x    = (const float*)d_in[0];
  const int*   pkd  = (const int*)d_in[1];
  const float* cb   = (const float*)d_in[2];
  const float* nrm  = (const float*)d_in[3];
  const float* rot  = (const float*)d_in[4];
  const float* bias = (const float*)d_in[5];
  float* out = (float*)d_out;

  const size_t y_bytes = (size_t)M_TOK * IN_K * 2;         // 32 MB bf16 rotated x
  u16*    y   = (u16*)d_ws;
  float2* tab = (float2*)((char*)d_ws + y_bytes);          // 2 KB
  u16*    wp  = (u16*)((char*)d_ws + y_bytes + 4096);      // 90 MB bf16 w'
  const size_t need_pre = y_bytes + 4096 + (size_t)OUT_N * IN_K * 2;
  const bool pre = ws_size >= need_pre;

  build_tab_kernel<<<1, 256, 0, stream>>>(cb, tab);
  rotate_kernel<<<dim3(M_TOK / 64, NGRP), 256, 0, stream>>>(x, rot, y);
  if (pre) {
    dequant_kernel<<<OUT_N, 256, 0, stream>>>(pkd, nrm, tab, wp);
    gemm_kernel<true><<<dim3(M_TOK / BM, OUT_N / BN), 256, 0, stream>>>(
        y, wp, pkd, tab, nrm, bias, out);
  } else {
    gemm_kernel<false><<<dim3(M_TOK / BM, OUT_N / BN), 256, 0, stream>>>(
        y, wp, pkd, tab, nrm, bias, out);
  }
}

// Round 4
// 673.374 us; speedup vs baseline: 1.2716x; 1.2716x over previous
//
#include <hip/hip_runtime.h>
#include <hip/hip_bf16.h>
#include <stdint.h>

#define M_TOK 4096
#define IN_K  4096
#define OUT_N 11008
#define NGRP  32

// ---- 8-phase-style gemm geometry: 256x128 tile, BK=64, ring-3 LDS ----
#define GBM 256
#define GBN 128
#define GBK 64
#define GNT (IN_K / GBK)              // 64 K-tiles
#define ABUF_ELEMS (GBM * GBK)        // 16384 u16 = 32 KB
#define BBUF_ELEMS (GBN * GBK)        // 8192  u16 = 16 KB
#define BUF_ELEMS  (ABUF_ELEMS + BBUF_ELEMS)  // 24576 u16 = 48 KB
#define N_TILES (OUT_N / GBN)         // 86
#define M_TILES (M_TOK / GBM)         // 16
#define N_WG (N_TILES * M_TILES)      // 1376 = 8 * 172

// ---- old fused-dequant fallback geometry ----
#define BM 128
#define BN 128
#define BK 64
#define NT (IN_K / BK)

typedef short bf16x8 __attribute__((ext_vector_type(8)));
typedef float f32x4  __attribute__((ext_vector_type(4)));
typedef unsigned short u16;
typedef unsigned int   u32;

__device__ __forceinline__ void glds16(const void* g, void* l) {
  __builtin_amdgcn_global_load_lds(
      (const __attribute__((address_space(1))) u32*)g,
      (__attribute__((address_space(3))) u32*)l, 16, 0, 0);
}

__device__ __forceinline__ u16 f2b(float f) {
  __hip_bfloat16 h = __float2bfloat16(f);
  return *(u16*)&h;
}
__device__ __forceinline__ u32 pack2(float a, float b) {
  return (u32)f2b(a) | ((u32)f2b(b) << 16);
}

#define BAR() asm volatile("s_barrier" ::: "memory")

// ---------------------------------------------------------------------------
// prep: tab[p]=(cb[p&15],cb[p>>4]); rtpre = bf16 R^T, pre-transposed and
// pre-swizzled so rotate can stage it with LINEAR global_load_lds.
// rtpre[row*128 + c*8 + e] = rot[h*128 + row], h = (c ^ (row&7))*8 + e.
// ---------------------------------------------------------------------------
__global__ void prep_kernel(const float* __restrict__ cb, const float* __restrict__ rot,
                            float2* __restrict__ tab, u16* __restrict__ rtpre) {
  const int t = threadIdx.x;
  if (blockIdx.x == 0) tab[t] = make_float2(cb[t & 15], cb[(t >> 4) & 15]);
  const int i = blockIdx.x * 256 + t;   // < 16384
  const int row = i >> 7;
  const int c = (i >> 3) & 15;
  const int e = i & 7;
  const int h = ((c ^ (row & 7)) << 3) | e;
  rtpre[i] = f2b(rot[h * 128 + row]);
}

// ---------------------------------------------------------------------------
// rotate: y[m][grp*128+g] = sum_h x[m][grp*128+h] * rot[h][g], bf16.
// Block = 128 m-rows x 1 group. Rt staged via 8 linear glds16 (pre-swizzled
// source), Xs reg-staged from float4 x loads. 4 waves (2x2), K=128 = 4 ksteps.
// ---------------------------------------------------------------------------
__global__ __launch_bounds__(256, 2)
void rotate_kernel(const float* __restrict__ x, const u16* __restrict__ rtpre,
                   u16* __restrict__ y) {
  __shared__ u16 Rt[128 * 128];   // [g][h] chunk-swizzled, 32 KB
  __shared__ u16 Xs[128 * 128];   // [m][h] chunk-swizzled, 32 KB
  const int t = threadIdx.x;
  const int m0 = blockIdx.x * 128;
  const int grp = blockIdx.y;

  // Rt: 8 issues x (256 threads x 16B) = 32 KB, LDS linear == rtpre layout
#pragma unroll
  for (int ii = 0; ii < 8; ++ii)
    glds16(rtpre + ii * 2048 + t * 8, (char*)Rt + ii * 4096 + t * 16);

  // Xs: thread t -> row m=t>>1, col-half t&1 (8 chunks of 8 elems)
  {
    const int m = t >> 1;
    const int half = t & 1;
    const float4* xs4 = (const float4*)(x + (size_t)(m0 + m) * IN_K + grp * 128);
#pragma unroll
    for (int cc = 0; cc < 8; ++cc) {
      const int g = half * 8 + cc;
      float4 f0 = xs4[g * 2];
      float4 f1 = xs4[g * 2 + 1];
      uint4 wv = make_uint4(pack2(f0.x, f0.y), pack2(f0.z, f0.w),
                            pack2(f1.x, f1.y), pack2(f1.z, f1.w));
      *(uint4*)&Xs[m * 128 + ((g ^ (m & 7)) << 3)] = wv;
    }
  }
  __syncthreads();

  const int lane = t & 63;
  const int w = t >> 6;
  const int wm = (w >> 1) * 64;
  const int wn = (w & 1) * 64;
  const int fr = lane & 15;
  const int q = lane >> 4;
  const int cs = fr & 7;

  f32x4 acc[4][4] = {};
#pragma unroll
  for (int ks = 0; ks < 4; ++ks) {
    bf16x8 a4[4], b4[4];
    const int ch = ((ks * 4 + q) ^ cs) << 3;
#pragma unroll
    for (int fi = 0; fi < 4; ++fi)
      a4[fi] = *(const bf16x8*)&Xs[(wm + fi * 16 + fr) * 128 + ch];
#pragma unroll
    for (int fj = 0; fj < 4; ++fj)
      b4[fj] = *(const bf16x8*)&Rt[(wn + fj * 16 + fr) * 128 + ch];
#pragma unroll
    for (int fi = 0; fi < 4; ++fi)
#pragma unroll
      for (int fj = 0; fj < 4; ++fj)
        acc[fi][fj] = __builtin_amdgcn_mfma_f32_16x16x32_bf16(a4[fi], b4[fj], acc[fi][fj], 0, 0, 0);
  }
#pragma unroll
  for (int fi = 0; fi < 4; ++fi)
#pragma unroll
    for (int fj = 0; fj < 4; ++fj)
#pragma unroll
      for (int rr = 0; rr < 4; ++rr)
        y[(size_t)(m0 + wm + fi * 16 + q * 4 + rr) * IN_K + grp * 128 + wn + fj * 16 + fr] =
            f2b(acc[fi][fj][rr]);
}

// ---------------------------------------------------------------------------
// dequant: w'[o][k] = cb[idx[o][k]] * norms[o][k/128], bf16. (unchanged)
// ---------------------------------------------------------------------------
__global__ __launch_bounds__(256)
void dequant_kernel(const int* __restrict__ packed, const float* __restrict__ norms,
                    const float2* __restrict__ tab, u16* __restrict__ wp) {
  const int o = blockIdx.x;
  const int t = threadIdx.x;
  const int* pb = packed + (size_t)o * (IN_K / 2) + t * 8;
  const float nm = norms[o * NGRP + (t >> 3)];
  int4 a = ((const int4*)pb)[0];
  int4 b = ((const int4*)pb)[1];
  int ps[8] = {a.x, a.y, a.z, a.w, b.x, b.y, b.z, b.w};
  u32 w[8];
#pragma unroll
  for (int j = 0; j < 8; ++j) {
    float2 c2 = tab[ps[j]];
    w[j] = pack2(c2.x * nm, c2.y * nm);
  }
  u32* dst = (u32*)(wp + (size_t)o * IN_K + t * 16);
  ((uint4*)dst)[0] = make_uint4(w[0], w[1], w[2], w[3]);
  ((uint4*)dst)[1] = make_uint4(w[4], w[5], w[6], w[7]);
}

// ---------------------------------------------------------------------------
// gemm8: C[m][n] = sum_k y[m][k]*w'[n][k] + bias[n].
// 256x128 tile, BK=64, 512 thr (8 waves, 4x2), ring-3 LDS (144 KB),
// 2 phases/K-tile, counted vmcnt(6), setprio around MFMA clusters.
// Ring-3 safety: staging for kt+2 targets buf (kt+2)%3, whose last reads
// (K-tile kt-1) completed before the barrier that ended kt-1 — issue order
// guarantees no write-while-read, regardless of when the async load lands.
// ---------------------------------------------------------------------------
__global__ __launch_bounds__(512, 2)
void gemm8_kernel(const u16* __restrict__ A, const u16* __restrict__ Bw,
                  const float* __restrict__ bias, float* __restrict__ C) {
  __shared__ u16 lds[3 * BUF_ELEMS];   // 144 KB

  const int t = threadIdx.x;
  // bijective XCD swizzle: 1376 = 8 * 172
  int wg = blockIdx.x;
  wg = (wg & 7) * (N_WG / 8) + (wg >> 3);
  const int nt = wg % N_TILES;
  const int mt = wg / N_TILES;
  const long m0 = (long)mt * GBM;
  const long n0 = (long)nt * GBN;

  // staging: thread t -> row t>>3 (of 64-row slab), 16B chunk t&7,
  // source column pre-swizzled so LDS stays linear (glds16 requirement).
  const int srow = t >> 3;
  const int scol = ((t & 7) ^ (srow & 7)) << 3;
  const u16* aSrc = A + (size_t)(m0 + srow) * IN_K + scol;
  const u16* bSrc = Bw + (size_t)(n0 + srow) * IN_K + scol;
  const int ldsByte = t * 16;

  auto stage3a = [&](u16* buf, int kt) {   // A slabs 0..2
#pragma unroll
    for (int ii = 0; ii < 3; ++ii)
      glds16(aSrc + (size_t)ii * 64 * IN_K + kt * GBK,
             (char*)buf + ii * 8192 + ldsByte);
  };
  auto stage3b = [&](u16* buf, int kt) {   // A slab 3 + B slabs 0..1
    glds16(aSrc + (size_t)3 * 64 * IN_K + kt * GBK,
           (char*)buf + 3 * 8192 + ldsByte);
#pragma unroll
    for (int ii = 0; ii < 2; ++ii)
      glds16(bSrc + (size_t)ii * 64 * IN_K + kt * GBK,
             (char*)buf + 2 * ABUF_ELEMS + ii * 8192 + ldsByte);
  };

  const int lane = t & 63;
  const int w = t >> 6;
  const int wmr = (w >> 1) * 64;   // wave A-row origin (4 m-waves)
  const int wnr = (w & 1) * 64;    // wave B-row origin (2 n-waves)
  const int fr = lane & 15;
  const int q = lane >> 4;
  const int cs = fr & 7;

  f32x4 acc[4][4] = {};
  bf16x8 av[4][2], bv[2][2];

  auto ldA = [&](const u16* abuf) {
#pragma unroll
    for (int fi = 0; fi < 4; ++fi) {
      const int row = wmr + fi * 16 + fr;
#pragma unroll
      for (int ks = 0; ks < 2; ++ks)
        av[fi][ks] = *(const bf16x8*)&abuf[row * 64 + (((ks * 4 + q) ^ cs) << 3)];
    }
  };
  auto ldB = [&](const u16* bbuf, int ph) {
#pragma unroll
    for (int fj = 0; fj < 2; ++fj) {
      const int row = wnr + ph * 32 + fj * 16 + fr;
#pragma unroll
      for (int ks = 0; ks < 2; ++ks)
        bv[fj][ks] = *(const bf16x8*)&bbuf[row * 64 + (((ks * 4 + q) ^ cs) << 3)];
    }
  };

#define MM(PH)                                                                   \
  do {                                                                           \
    _Pragma("unroll") for (int ks = 0; ks < 2; ++ks)                             \
        _Pragma("unroll") for (int fi = 0; fi < 4; ++fi)                         \
            _Pragma("unroll") for (int fj = 0; fj < 2; ++fj)                     \
                acc[fi][(PH)*2 + fj] = __builtin_amdgcn_mfma_f32_16x16x32_bf16(  \
                    av[fi][ks], bv[fj][ks], acc[fi][(PH)*2 + fj], 0, 0, 0);      \
  } while (0)

  // prologue: stage K-tiles 0 and 1
  stage3a(lds, 0); stage3b(lds, 0);
  stage3a(lds + BUF_ELEMS, 1); stage3b(lds + BUF_ELEMS, 1);
  asm volatile("s_waitcnt vmcnt(6)" ::: "memory");   // K-tile 0 landed
  BAR();

  int b0 = 0, b2 = 2;
  for (int kt = 0; kt < GNT; ++kt) {
    const u16* abuf = lds + b0 * BUF_ELEMS;
    const u16* bbuf = abuf + ABUF_ELEMS;
    u16* sbuf = lds + b2 * BUF_ELEMS;
    const bool st = (kt + 2 < GNT);

    // ---- phase 0: n-half 0, full K=64 ----
    ldA(abuf);
    ldB(bbuf, 0);
    if (st) stage3a(sbuf, kt + 2);
    BAR();
    __builtin_amdgcn_s_setprio(1);
    MM(0);
    __builtin_amdgcn_s_setprio(0);
    BAR();

    // ---- phase 1: n-half 1 (av reused) ----
    ldB(bbuf, 1);
    if (st) {
      stage3b(sbuf, kt + 2);
      asm volatile("s_waitcnt vmcnt(6)" ::: "memory");  // K-tile kt+1 landed
    } else {
      asm volatile("s_waitcnt vmcnt(0)" ::: "memory");  // drain tail
    }
    BAR();
    __builtin_amdgcn_s_setprio(1);
    MM(1);
    __builtin_amdgcn_s_setprio(0);
    BAR();

    b0 = (b0 == 2) ? 0 : b0 + 1;
    b2 = (b2 == 2) ? 0 : b2 + 1;
  }
#undef MM

  // epilogue: per-wave 64x64 C block at (m0+wmr, n0+wnr)
#pragma unroll
  for (int fj = 0; fj < 4; ++fj) {
    const long col = n0 + wnr + fj * 16 + fr;
    const float bvs = bias[col];
#pragma unroll
    for (int fi = 0; fi < 4; ++fi) {
      const long row = m0 + wmr + fi * 16 + q * 4;
#pragma unroll
      for (int rr = 0; rr < 4; ++rr)
        C[(size_t)(row + rr) * OUT_N + col] = acc[fi][fj][rr] + bvs;
    }
  }
}

// ---------------------------------------------------------------------------
// fallback fused-dequant gemm (round-2 structure, only used if ws too small)
// ---------------------------------------------------------------------------
__global__ __launch_bounds__(256, 2)
void gemm_fused_kernel(const u16* __restrict__ A, const int* __restrict__ packed,
                       const float2* __restrict__ tab, const float* __restrict__ norms,
                       const float* __restrict__ bias, float* __restrict__ C) {
  __shared__ u16 As[2][BM * BK];
  __shared__ u16 Bs[2][BM * BK];

  const int t = threadIdx.x;
  const int m0 = blockIdx.x * BM;
  const int n0 = blockIdx.y * BN;

  const int srow = t >> 3;
  const int scol = (((t & 7) ^ (srow & 7)) << 3);
  const u32 luni = (u32)(t & 192) * 16;

  const int fro = t >> 1;
  const int kh = t & 1;

  const int lane = t & 63;
  const int wv = t >> 6;
  const int wm = (wv >> 1) * 64;
  const int wn = (wv & 1) * 64;
  const int fr = lane & 15;
  const int q = lane >> 4;
  const int sw = fr & 7;

  f32x4 acc[4][4] = {};
  int4 pk[4];

  auto stageA = [&](int buf, int kt) {
#pragma unroll
    for (int i = 0; i < 4; ++i)
      glds16(A + (size_t)(m0 + i * 32 + srow) * IN_K + kt * BK + scol,
             (char*)(&As[buf][0]) + i * 4096 + luni);
  };
  auto loadBidx = [&](int kt) {
    const int4* pb =
        (const int4*)(packed + (size_t)(n0 + fro) * (IN_K / 2) + kt * (BK / 2) + kh * 16);
#pragma unroll
    for (int i = 0; i < 4; ++i) pk[i] = pb[i];
  };
  auto dequantB = [&](int buf, int kt) {
    const float nm = norms[(n0 + fro) * NGRP + (kt >> 1)];
#pragma unroll
    for (int jj = 0; jj < 4; ++jj) {
      int pv[4] = {pk[jj].x, pk[jj].y, pk[jj].z, pk[jj].w};
      u32 wq[4];
#pragma unroll
      for (int qq = 0; qq < 4; ++qq) {
        float2 c2 = tab[pv[qq]];
        wq[qq] = pack2(c2.x * nm, c2.y * nm);
      }
      uint4* dst = (uint4*)((char*)(&Bs[buf][0]) + fro * (BK * 2) +
                            (((kh * 4 + jj) ^ (fro & 7)) << 4));
      *dst = make_uint4(wq[0], wq[1], wq[2], wq[3]);
    }
  };
  auto compute = [&](int buf) {
#pragma unroll
    for (int ks = 0; ks < 2; ++ks) {
      bf16x8 a8[4], b8[4];
#pragma unroll
      for (int fi = 0; fi < 4; ++fi)
        a8[fi] = *(const bf16x8*)&As[buf][(wm + fi * 16 + fr) * BK + (((ks * 4 + q) ^ sw) << 3)];
#pragma unroll
      for (int fj = 0; fj < 4; ++fj)
        b8[fj] = *(const bf16x8*)&Bs[buf][(wn + fj * 16 + fr) * BK + (((ks * 4 + q) ^ sw) << 3)];
#pragma unroll
      for (int fi = 0; fi < 4; ++fi)
#pragma unroll
        for (int fj = 0; fj < 4; ++fj)
          acc[fi][fj] =
              __builtin_amdgcn_mfma_f32_16x16x32_bf16(a8[fi], b8[fj], acc[fi][fj], 0, 0, 0);
    }
  };

  int buf = 0;
  stageA(0, 0);
  loadBidx(0);
  dequantB(0, 0);
  __syncthreads();

  for (int kt = 0; kt < NT; ++kt) {
    const int nxt = kt + 1;
    if (nxt < NT) {
      stageA(buf ^ 1, nxt);
      loadBidx(nxt);
    }
    compute(buf);
    if (nxt < NT) dequantB(buf ^ 1, nxt);
    __syncthreads();
    buf ^= 1;
  }

#pragma unroll
  for (int fj = 0; fj < 4; ++fj) {
    const int col = n0 + wn + fj * 16 + fr;
    const float bvs = bias[col];
#pragma unroll
    for (int fi = 0; fi < 4; ++fi) {
      const int row = m0 + wm + fi * 16 + q * 4;
#pragma unroll
      for (int rr = 0; rr < 4; ++rr)
        C[(size_t)(row + rr) * OUT_N + col] = acc[fi][fj][rr] + bvs;
    }
  }
}

extern "C" void kernel_launch(void* const* d_in, const int* in_sizes, int n_in,
                              void* d_out, int out_size, void* d_ws, size_t ws_size,
                              hipStream_t stream) {
  const float* x    = (const float*)d_in[0];
  const int*   pkd  = (const int*)d_in[1];
  const float* cb   = (const float*)d_in[2];
  const float* nrm  = (const float*)d_in[3];
  const float* rot  = (const float*)d_in[4];
  const float* bias = (const float*)d_in[5];
  float* out = (float*)d_out;

  const size_t y_bytes = (size_t)M_TOK * IN_K * 2;           // 32 MB
  u16*    y     = (u16*)d_ws;
  float2* tab   = (float2*)((char*)d_ws + y_bytes);          // 2 KB (pad 4K)
  u16*    rtpre = (u16*)((char*)d_ws + y_bytes + 4096);      // 32 KB
  u16*    wp    = (u16*)((char*)d_ws + y_bytes + 4096 + 32768);
  const size_t need_pre = y_bytes + 4096 + 32768 + (size_t)OUT_N * IN_K * 2;

  prep_kernel<<<64, 256, 0, stream>>>(cb, rot, tab, rtpre);
  rotate_kernel<<<dim3(M_TOK / 128, NGRP), 256, 0, stream>>>(x, rtpre, y);
  if (ws_size >= need_pre) {
    dequant_kernel<<<OUT_N, 256, 0, stream>>>(pkd, nrm, tab, wp);
    gemm8_kernel<<<N_WG, 512, 0, stream>>>(y, wp, bias, out);
  } else {
    gemm_fused_kernel<<<dim3(M_TOK / BM, OUT_N / BN), 256, 0, stream>>>(
        y, pkd, tab, nrm, bias, out);
  }
}